// Round 1
// baseline (569.144 us; speedup 1.0000x reference)
//
#include <hip/hip_runtime.h>
#include <math.h>

typedef unsigned long long u64;
typedef unsigned int u32;

#define NP 34125
#define NB 4
#define NTOP 5000
#define TOPK 750
#define NW 79          // ceil(5000/64)
#define TPAD 5120      // padded top-K stride
#define SORTN 8192
#define MWORDS 202240  // triangular mask words per image: 64*sum_{c=0..78}(79-c)

// ---- exact-order f32 IoU matching the JAX reference elementwise ops ----
__device__ __forceinline__ float iou_ref(float4 a, float4 b) {
  float areaA = __fmul_rn(__fsub_rn(a.z, a.x), __fsub_rn(a.w, a.y));
  float areaB = __fmul_rn(__fsub_rn(b.z, b.x), __fsub_rn(b.w, b.y));
  float iw = fmaxf(__fsub_rn(fminf(a.z, b.z), fmaxf(a.x, b.x)), 0.0f);
  float ih = fmaxf(__fsub_rn(fminf(a.w, b.w), fmaxf(a.y, b.y)), 0.0f);
  float inter = __fmul_rn(iw, ih);
  float denom = __fsub_rn(__fadd_rn(areaA, areaB), inter);
  return inter / denom;  // 0/0 -> NaN for zero-pad boxes; NaN>0.3f is false (safe)
}

// triangular row offset (in u64 words) of mask row i within one image
__device__ __forceinline__ int row_off_words(int i) {
  int ci = i >> 6;
  int r = i & 63;
  int base = ((ci * 79 - ((ci * (ci - 1)) >> 1)) << 6);
  return base + r * (79 - ci);
}

__global__ void k_zero(float* out, u32* hist, u32* cnt) {
  int t = blockIdx.x * 256 + threadIdx.x;
  if (t < 30000) out[t] = 0.0f;
  if (t < 4096) hist[t] = 0u;
  if (t < 4) cnt[t] = 0u;
}

__global__ void k_decode(const float4* loc, const float* conf, const float4* prior,
                         float4* dec, u32* hist) {
  int p = blockIdx.x * 256 + threadIdx.x;
  int img = blockIdx.y;
  if (p >= NP) return;
  float4 L = loc[(size_t)img * NP + p];
  float4 Pr = prior[p];
  // xy = prior_xy + (loc_xy * 0.1) * prior_wh   (no FMA contraction: explicit _rn ops)
  float ex = __fmul_rn(__fmul_rn(L.x, 0.1f), Pr.z);
  float ey = __fmul_rn(__fmul_rn(L.y, 0.1f), Pr.w);
  float cx = __fadd_rn(Pr.x, ex);
  float cy = __fadd_rn(Pr.y, ey);
  // wh = prior_wh * exp(loc_wh * 0.2) ; exp via double = correctly-rounded f32 exp
  float ww = __fmul_rn(Pr.z, (float)exp((double)__fmul_rn(L.z, 0.2f)));
  float hh = __fmul_rn(Pr.w, (float)exp((double)__fmul_rn(L.w, 0.2f)));
  float x1 = __fsub_rn(cx, __fmul_rn(ww, 0.5f));
  float y1 = __fsub_rn(cy, __fmul_rn(hh, 0.5f));
  float x2 = __fadd_rn(x1, ww);
  float y2 = __fadd_rn(y1, hh);
  dec[(size_t)img * NP + p] = make_float4(x1, y1, x2, y2);
  float s = conf[((size_t)img * NP + p) * 2 + 1];
  if (s > 0.05f) {
    int bin = (int)(s * 1024.0f); if (bin > 1023) bin = 1023;
    atomicAdd(&hist[img * 1024 + bin], 1u);
  }
}

// one wave per image: find cutoff bin so that suffix-count >= NTOP
__global__ __launch_bounds__(64) void k_cutoff(const u32* hist, int* cut) {
  int img = blockIdx.x;
  int lane = threadIdx.x;
  const u32* h = hist + img * 1024;
  int start = 1023 - lane * 16;  // lane covers bins [start-15, start], descending order
  int local = 0;
  for (int q = 0; q < 16; ++q) local += (int)h[start - q];
  int incl = local;
  for (int d = 1; d < 64; d <<= 1) {
    int v = __shfl_up(incl, d);
    if (lane >= d) incl += v;
  }
  u64 hit = __ballot(incl >= NTOP);
  if (hit != 0ull) {
    int f = __builtin_ctzll(hit);
    if (lane == f) {
      int acc = incl - local;
      int cb = 0;
      for (int q = 0; q < 16; ++q) {
        acc += (int)h[start - q];
        if (acc >= NTOP) { cb = start - q; break; }
      }
      cut[img] = cb;
    }
  } else if (lane == 0) {
    cut[img] = 0;  // fewer than NTOP valid scores
  }
}

// per image: collect candidates, bitonic-sort 8192 u64 keys in dynamic LDS,
// emit sorted top-5000 (score, box) + validity bitmask
__global__ __launch_bounds__(1024) void k_select(const float* conf, const int* cut, u32* cnt,
                                                 const float4* dec, float* tscore,
                                                 float4* tbox, u64* vmask) {
  extern __shared__ u64 keys[];  // 8192 * 8B = 64KB
  int img = blockIdx.x;
  int tid = threadIdx.x;
  int lane = tid & 63;
  int cb = cut[img];
  for (int i = tid; i < SORTN; i += 1024) keys[i] = ~0ull;
  __syncthreads();
  // collect candidates (wave-aggregated global atomic for positions)
  for (int p = tid; p < NP; p += 1024) {
    float s = conf[((size_t)img * NP + p) * 2 + 1];
    bool take = false;
    if (s > 0.05f) {
      int bin = (int)(s * 1024.0f); if (bin > 1023) bin = 1023;
      take = (bin >= cb);
    }
    if (take) {
      u64 m = __ballot(1);
      int leader = __builtin_ctzll(m);
      int rank = __builtin_popcountll(m & ((1ull << lane) - 1ull));
      int base = 0;
      if (lane == leader) base = (int)atomicAdd(&cnt[img], (u32)__builtin_popcountll(m));
      base = __shfl(base, leader);
      int pos = base + rank;
      if (pos < SORTN)
        keys[pos] = (((u64)(~__float_as_uint(s))) << 32) | (u32)p;
    }
  }
  __syncthreads();
  // bitonic sort ascending: key = (~score_bits, idx) => score desc, idx asc (lax.top_k ties)
  for (int k = 2; k <= SORTN; k <<= 1) {
    for (int j = k >> 1; j > 0; j >>= 1) {
      for (int idx = tid; idx < SORTN; idx += 1024) {
        int ixj = idx ^ j;
        if (ixj > idx) {
          u64 a = keys[idx], b = keys[ixj];
          bool up = ((idx & k) == 0);
          if ((a > b) == up) { keys[idx] = b; keys[ixj] = a; }
        }
      }
      __syncthreads();
    }
  }
  // emit top-5000
  for (int i = tid; i < NTOP; i += 1024) {
    u64 key = keys[i];
    u32 sb = ~(u32)(key >> 32);
    float s = __uint_as_float(sb);
    u32 pidx = (u32)(key & 0xffffffffu);
    tscore[img * TPAD + i] = s;
    float4 bx;
    if (key != ~0ull) bx = dec[(size_t)img * NP + pidx];
    else bx = make_float4(0.f, 0.f, 0.f, 0.f);
    tbox[img * TPAD + i] = bx;
    bool valid = (key != ~0ull) && (s > 0.05f);
    u64 bal = __ballot(valid);
    if (lane == 0) vmask[img * 80 + (i >> 6)] = bal;  // wave == one 64-aligned word
  }
}

// parallel suppression-bitmask: 64x64 tiles, upper triangle, triangular storage
__global__ __launch_bounds__(64) void k_mask(const float4* tbox, u64* mask) {
  int ci = blockIdx.x, cj = blockIdx.y, img = blockIdx.z;
  if (cj < ci) return;
  int lane = threadIdx.x;
  __shared__ float4 jb[64];
  int j0 = cj * 64;
  int jj = j0 + lane;
  jb[lane] = (jj < NTOP) ? tbox[img * TPAD + jj] : make_float4(0.f, 0.f, 0.f, 0.f);
  __syncthreads();
  int i = ci * 64 + lane;
  if (i >= NTOP) return;
  float4 bi = tbox[img * TPAD + i];
  u64 word = 0;
  for (int q = 0; q < 64; ++q) {
    int j = j0 + q;
    if (j > i && j < NTOP) {
      if (iou_ref(bi, jb[q]) > 0.3f) word |= (1ull << q);
    }
  }
  u64* mrow = mask + (size_t)img * MWORDS + row_off_words(i);
  mrow[cj - ci] = word;
}

// serial greedy NMS: one wave per image; each iteration keeps exactly one box
__global__ __launch_bounds__(64) void k_nms(const float* tscore, const float4* tbox,
                                            const u64* vmask, const u64* mask, float* out) {
  int img = blockIdx.x;
  int lane = threadIdx.x;
  __shared__ u64 rem[80];
  __shared__ u64 vld[80];
  __shared__ int list[TOPK];
  for (int wd = lane; wd < 80; wd += 64) {
    rem[wd] = 0ull;
    vld[wd] = (wd < NW) ? vmask[img * 80 + wd] : 0ull;
  }
  __syncthreads();
  int nk = 0;
  const u64* mimg = mask + (size_t)img * MWORDS;
  for (int w = 0; w < NW; ++w) {
    u64 prog = ~0ull;
    while (true) {
      u64 live = vld[w] & ~rem[w] & prog;  // uniform LDS broadcast read
      if (live == 0ull) break;
      int k = __builtin_ctzll(live);
      int i = (w << 6) + k;
      if (lane == 0) list[nk] = i;
      ++nk;
      if (nk == TOPK) { w = NW; break; }  // later keeps can't affect output
      prog = ~((2ull << k) - 1ull);       // bits strictly above k (k=63 -> 0)
      // OR suppression row of kept box i (words w..78), lane-parallel
      const u64* row = mimg + row_off_words(i);
      int nwr = NW - w;
      if (lane < nwr) rem[w + lane] |= row[lane];
      int l2 = lane + 64;
      if (l2 < nwr) rem[w + l2] |= row[l2];
    }
  }
  __syncthreads();
  float* o = out + (size_t)(img * 2 + 1) * TOPK * 5;
  for (int r = lane; r < nk; r += 64) {
    int i = list[r];
    float s = tscore[img * TPAD + i];
    float4 b = tbox[img * TPAD + i];
    o[r * 5 + 0] = s;
    o[r * 5 + 1] = b.x;
    o[r * 5 + 2] = b.y;
    o[r * 5 + 3] = b.z;
    o[r * 5 + 4] = b.w;
  }
}

extern "C" void kernel_launch(void* const* d_in, const int* in_sizes, int n_in,
                              void* d_out, int out_size, void* d_ws, size_t ws_size,
                              hipStream_t stream) {
  const float4* loc   = (const float4*)d_in[0];
  const float*  conf  = (const float*)d_in[1];
  const float4* prior = (const float4*)d_in[2];
  float* out = (float*)d_out;
  char* ws = (char*)d_ws;

  // ws layout (256B-aligned offsets), total ~8.7MB
  float4* dec    = (float4*)(ws + 0);          // 4*34125*16 = 2,184,000
  u32*    hist   = (u32*)  (ws + 2184192);     // 4*1024*4   = 16,384
  u32*    cnt    = (u32*)  (ws + 2200576);     // 16
  int*    cut    = (int*)  (ws + 2200832);     // 16
  float*  tscore = (float*)(ws + 2201088);     // 4*5120*4   = 81,920
  float4* tbox   = (float4*)(ws + 2283008);    // 4*5120*16  = 327,680
  u64*    vmaskp = (u64*)  (ws + 2610688);     // 4*80*8     = 2,560
  u64*    maskp  = (u64*)  (ws + 2613504);     // 4*202240*8 = 6,471,680  -> end 9,085,184

  k_zero<<<dim3(118), 256, 0, stream>>>(out, hist, cnt);
  k_decode<<<dim3((NP + 255) / 256, NB), 256, 0, stream>>>(loc, conf, prior, dec, hist);
  k_cutoff<<<NB, 64, 0, stream>>>(hist, cut);
  k_select<<<NB, 1024, SORTN * sizeof(u64), stream>>>(conf, cut, cnt, dec, tscore, tbox, vmaskp);
  k_mask<<<dim3(NW, NW, NB), 64, 0, stream>>>(tbox, maskp);
  k_nms<<<NB, 64, 0, stream>>>(tscore, tbox, vmaskp, maskp, out);
}

// Round 2
// 529.817 us; speedup vs baseline: 1.0742x; 1.0742x over previous
//
#include <hip/hip_runtime.h>
#include <math.h>

typedef unsigned long long u64;
typedef unsigned int u32;

#define NP 34125
#define NB 4
#define NTOP 5000
#define TOPK 750
#define NW 79          // ceil(5000/64)
#define TPAD 5120      // padded top-K stride
#define SORTN 8192
#define MWORDS 202240  // triangular mask words per image: 64*sum_{c=0..78}(79-c)

// ---- exact-order f32 IoU matching the JAX reference elementwise ops ----
__device__ __forceinline__ float iou_ref(float4 a, float4 b) {
  float areaA = __fmul_rn(__fsub_rn(a.z, a.x), __fsub_rn(a.w, a.y));
  float areaB = __fmul_rn(__fsub_rn(b.z, b.x), __fsub_rn(b.w, b.y));
  float iw = fmaxf(__fsub_rn(fminf(a.z, b.z), fmaxf(a.x, b.x)), 0.0f);
  float ih = fmaxf(__fsub_rn(fminf(a.w, b.w), fmaxf(a.y, b.y)), 0.0f);
  float inter = __fmul_rn(iw, ih);
  float denom = __fsub_rn(__fadd_rn(areaA, areaB), inter);
  return inter / denom;  // 0/0 -> NaN for zero-pad boxes; NaN>0.3f is false (safe)
}

// triangular row offset (in u64 words) of mask row i within one image
__device__ __forceinline__ int row_off_words(int i) {
  int ci = i >> 6;
  int r = i & 63;
  int base = ((ci * 79 - ((ci * (ci - 1)) >> 1)) << 6);
  return base + r * (79 - ci);
}

__device__ __forceinline__ u64 wave_or64(u64 x) {
  for (int d = 1; d < 64; d <<= 1) x |= __shfl_xor(x, d);
  return x;
}

__global__ void k_zero(float* out, u32* hist, u32* cnt) {
  int t = blockIdx.x * 256 + threadIdx.x;
  if (t < 30000) out[t] = 0.0f;
  if (t < 4096) hist[t] = 0u;
  if (t < 4) cnt[t] = 0u;
}

__global__ void k_decode(const float4* loc, const float* conf, const float4* prior,
                         float4* dec, u32* hist) {
  int p = blockIdx.x * 256 + threadIdx.x;
  int img = blockIdx.y;
  if (p >= NP) return;
  float4 L = loc[(size_t)img * NP + p];
  float4 Pr = prior[p];
  // xy = prior_xy + (loc_xy * 0.1) * prior_wh   (no FMA contraction: explicit _rn ops)
  float ex = __fmul_rn(__fmul_rn(L.x, 0.1f), Pr.z);
  float ey = __fmul_rn(__fmul_rn(L.y, 0.1f), Pr.w);
  float cx = __fadd_rn(Pr.x, ex);
  float cy = __fadd_rn(Pr.y, ey);
  // wh = prior_wh * exp(loc_wh * 0.2) ; exp via double = correctly-rounded f32 exp
  float ww = __fmul_rn(Pr.z, (float)exp((double)__fmul_rn(L.z, 0.2f)));
  float hh = __fmul_rn(Pr.w, (float)exp((double)__fmul_rn(L.w, 0.2f)));
  float x1 = __fsub_rn(cx, __fmul_rn(ww, 0.5f));
  float y1 = __fsub_rn(cy, __fmul_rn(hh, 0.5f));
  float x2 = __fadd_rn(x1, ww);
  float y2 = __fadd_rn(y1, hh);
  dec[(size_t)img * NP + p] = make_float4(x1, y1, x2, y2);
  float s = conf[((size_t)img * NP + p) * 2 + 1];
  if (s > 0.05f) {
    int bin = (int)(s * 1024.0f); if (bin > 1023) bin = 1023;
    atomicAdd(&hist[img * 1024 + bin], 1u);
  }
}

// one wave per image: find cutoff bin so that suffix-count >= NTOP
__global__ __launch_bounds__(64) void k_cutoff(const u32* hist, int* cut) {
  int img = blockIdx.x;
  int lane = threadIdx.x;
  const u32* h = hist + img * 1024;
  int start = 1023 - lane * 16;  // lane covers bins [start-15, start], descending order
  int local = 0;
  for (int q = 0; q < 16; ++q) local += (int)h[start - q];
  int incl = local;
  for (int d = 1; d < 64; d <<= 1) {
    int v = __shfl_up(incl, d);
    if (lane >= d) incl += v;
  }
  u64 hit = __ballot(incl >= NTOP);
  if (hit != 0ull) {
    int f = __builtin_ctzll(hit);
    if (lane == f) {
      int acc = incl - local;
      int cb = 0;
      for (int q = 0; q < 16; ++q) {
        acc += (int)h[start - q];
        if (acc >= NTOP) { cb = start - q; break; }
      }
      cut[img] = cb;
    }
  } else if (lane == 0) {
    cut[img] = 0;  // fewer than NTOP valid scores
  }
}

// per image: collect candidates, bitonic-sort 8192 u64 keys in dynamic LDS,
// emit sorted top-5000 (score, box) + validity bitmask
__global__ __launch_bounds__(1024) void k_select(const float* conf, const int* cut, u32* cnt,
                                                 const float4* dec, float* tscore,
                                                 float4* tbox, u64* vmask) {
  extern __shared__ u64 keys[];  // 8192 * 8B = 64KB
  int img = blockIdx.x;
  int tid = threadIdx.x;
  int lane = tid & 63;
  int cb = cut[img];
  for (int i = tid; i < SORTN; i += 1024) keys[i] = ~0ull;
  __syncthreads();
  // collect candidates (wave-aggregated global atomic for positions)
  for (int p = tid; p < NP; p += 1024) {
    float s = conf[((size_t)img * NP + p) * 2 + 1];
    bool take = false;
    if (s > 0.05f) {
      int bin = (int)(s * 1024.0f); if (bin > 1023) bin = 1023;
      take = (bin >= cb);
    }
    if (take) {
      u64 m = __ballot(1);
      int leader = __builtin_ctzll(m);
      int rank = __builtin_popcountll(m & ((1ull << lane) - 1ull));
      int base = 0;
      if (lane == leader) base = (int)atomicAdd(&cnt[img], (u32)__builtin_popcountll(m));
      base = __shfl(base, leader);
      int pos = base + rank;
      if (pos < SORTN)
        keys[pos] = (((u64)(~__float_as_uint(s))) << 32) | (u32)p;
    }
  }
  __syncthreads();
  // bitonic sort ascending: key = (~score_bits, idx) => score desc, idx asc (lax.top_k ties)
  for (int k = 2; k <= SORTN; k <<= 1) {
    for (int j = k >> 1; j > 0; j >>= 1) {
      for (int idx = tid; idx < SORTN; idx += 1024) {
        int ixj = idx ^ j;
        if (ixj > idx) {
          u64 a = keys[idx], b = keys[ixj];
          bool up = ((idx & k) == 0);
          if ((a > b) == up) { keys[idx] = b; keys[ixj] = a; }
        }
      }
      __syncthreads();
    }
  }
  // emit top-5000
  for (int i = tid; i < NTOP; i += 1024) {
    u64 key = keys[i];
    u32 sb = ~(u32)(key >> 32);
    float s = __uint_as_float(sb);
    u32 pidx = (u32)(key & 0xffffffffu);
    tscore[img * TPAD + i] = s;
    float4 bx;
    if (key != ~0ull) bx = dec[(size_t)img * NP + pidx];
    else bx = make_float4(0.f, 0.f, 0.f, 0.f);
    tbox[img * TPAD + i] = bx;
    bool valid = (key != ~0ull) && (s > 0.05f);
    u64 bal = __ballot(valid);
    if (lane == 0) vmask[img * 80 + (i >> 6)] = bal;  // wave == one 64-aligned word
  }
}

// parallel suppression-bitmask: 64x64 tiles, upper triangle, triangular storage
__global__ __launch_bounds__(64) void k_mask(const float4* tbox, u64* mask) {
  int ci = blockIdx.x, cj = blockIdx.y, img = blockIdx.z;
  if (cj < ci) return;
  int lane = threadIdx.x;
  __shared__ float4 jb[64];
  int j0 = cj * 64;
  int jj = j0 + lane;
  jb[lane] = (jj < NTOP) ? tbox[img * TPAD + jj] : make_float4(0.f, 0.f, 0.f, 0.f);
  __syncthreads();
  int i = ci * 64 + lane;
  if (i >= NTOP) return;
  float4 bi = tbox[img * TPAD + i];
  u64 word = 0;
  for (int q = 0; q < 64; ++q) {
    int j = j0 + q;
    if (j > i && j < NTOP) {
      if (iou_ref(bi, jb[q]) > 0.3f) word |= (1ull << q);
    }
  }
  u64* mrow = mask + (size_t)img * MWORDS + row_off_words(i);
  mrow[cj - ci] = word;
}

// greedy NMS, word-block parallel form: one wave per image.
// Per 64-candidate word: resolve the greedy fixpoint in-register using the
// diagonal 64x64 tile (ready-set iteration: a live candidate with no live
// lower-index overlapper is definitely kept). Cross-word suppression is a
// bulk owner-aligned OR with all kept rows' loads in flight simultaneously
// -> one memory latency per WORD, not per kept box.
__global__ __launch_bounds__(64) void k_nms(const float* tscore, const float4* tbox,
                                            const u64* vmask, const u64* mask, float* out) {
  int img = blockIdx.x;
  int lane = threadIdx.x;
  const u64* mimg = mask + (size_t)img * MWORDS;

  // distributed suppression/validity state: lane l owns words l and l+64
  u64 rem_lo = 0ull, rem_hi = 0ull;
  u64 vld_lo = (lane < NW) ? vmask[img * 80 + lane] : 0ull;
  u64 vld_hi = (lane + 64 < NW) ? vmask[img * 80 + lane + 64] : 0ull;

  __shared__ int list[TOPK];
  int nk = 0;

  // prefetch diagonal tile of word 0: lane k holds self-word of row k
  u64 mydiag = mimg[row_off_words(lane)];

  for (int w = 0; w < NW; ++w) {
    // broadcast rem[w], vld[w] from owning lane
    u64 remw = (w < 64) ? __shfl(rem_lo, w) : __shfl(rem_hi, w - 64);
    u64 vldw = (w < 64) ? __shfl(vld_lo, w) : __shfl(vld_hi, w - 64);
    u64 live = vldw & ~remw;
    u64 diag = mydiag;

    // prefetch next word's diagonal (overlaps with resolve + bulk latency)
    if (w + 1 < NW) {
      int i1 = ((w + 1) << 6) + lane;
      mydiag = (i1 < NTOP) ? mimg[row_off_words(i1)] : 0ull;
    }

    if (live == 0ull) continue;

    // intra-word greedy fixpoint (final kept mask in ascending bit order
    // == greedy keep order within the word)
    u64 kept = 0ull;
    while (live) {
      u64 contrib = ((live >> lane) & 1ull) ? diag : 0ull;
      u64 supany = wave_or64(contrib);
      u64 ready = live & ~supany;          // no live lower overlapper -> kept
      kept |= ready;
      u64 contrib2 = ((ready >> lane) & 1ull) ? diag : 0ull;
      u64 supready = wave_or64(contrib2);
      live &= ~(ready | supready);
    }

    // append kept (ascending index) to list, honoring the 750 cut
    int cap = TOPK - nk;
    int rank = __builtin_popcountll(kept & ((1ull << lane) - 1ull));
    if (((kept >> lane) & 1ull) && rank < cap) list[nk + rank] = (w << 6) + lane;
    int nkw = __builtin_popcountll(kept);
    nk += (nkw < cap) ? nkw : cap;
    if (nk >= TOPK) break;

    // bulk cross-word suppression: owner-aligned parallel loads, all kept
    // rows in flight at once
    u64 kk = kept;
    while (kk) {
      int k = __builtin_ctzll(kk);
      kk &= kk - 1ull;
      const u64* row = mimg + row_off_words((w << 6) + k);  // words w..78
      if (lane > w) rem_lo |= row[lane - w];                // word `lane`
      int hw = 64 + lane;
      if (hw > w && hw < NW) rem_hi |= row[hw - w];         // word 64+lane
    }
  }

  __syncthreads();
  float* o = out + (size_t)(img * 2 + 1) * TOPK * 5;
  for (int r = lane; r < nk; r += 64) {
    int i = list[r];
    float s = tscore[img * TPAD + i];
    float4 b = tbox[img * TPAD + i];
    o[r * 5 + 0] = s;
    o[r * 5 + 1] = b.x;
    o[r * 5 + 2] = b.y;
    o[r * 5 + 3] = b.z;
    o[r * 5 + 4] = b.w;
  }
}

extern "C" void kernel_launch(void* const* d_in, const int* in_sizes, int n_in,
                              void* d_out, int out_size, void* d_ws, size_t ws_size,
                              hipStream_t stream) {
  const float4* loc   = (const float4*)d_in[0];
  const float*  conf  = (const float*)d_in[1];
  const float4* prior = (const float4*)d_in[2];
  float* out = (float*)d_out;
  char* ws = (char*)d_ws;

  // ws layout (256B-aligned offsets), total ~8.7MB
  float4* dec    = (float4*)(ws + 0);          // 4*34125*16 = 2,184,000
  u32*    hist   = (u32*)  (ws + 2184192);     // 4*1024*4   = 16,384
  u32*    cnt    = (u32*)  (ws + 2200576);     // 16
  int*    cut    = (int*)  (ws + 2200832);     // 16
  float*  tscore = (float*)(ws + 2201088);     // 4*5120*4   = 81,920
  float4* tbox   = (float4*)(ws + 2283008);    // 4*5120*16  = 327,680
  u64*    vmaskp = (u64*)  (ws + 2610688);     // 4*80*8     = 2,560
  u64*    maskp  = (u64*)  (ws + 2613504);     // 4*202240*8 = 6,471,680  -> end 9,085,184

  k_zero<<<dim3(118), 256, 0, stream>>>(out, hist, cnt);
  k_decode<<<dim3((NP + 255) / 256, NB), 256, 0, stream>>>(loc, conf, prior, dec, hist);
  k_cutoff<<<NB, 64, 0, stream>>>(hist, cut);
  k_select<<<NB, 1024, SORTN * sizeof(u64), stream>>>(conf, cut, cnt, dec, tscore, tbox, vmaskp);
  k_mask<<<dim3(NW, NW, NB), 64, 0, stream>>>(tbox, maskp);
  k_nms<<<NB, 64, 0, stream>>>(tscore, tbox, vmaskp, maskp, out);
}

// Round 3
// 414.256 us; speedup vs baseline: 1.3739x; 1.2790x over previous
//
#include <hip/hip_runtime.h>
#include <math.h>

typedef unsigned long long u64;
typedef unsigned int u32;

#define NP 34125
#define NB 4
#define NTOP 5000
#define TOPK 750
#define NW 79          // ceil(5000/64)
#define TPAD 5120      // padded top-K stride
#define SORTN 8192
#define MWORDS 202240  // triangular mask words per image: 64*sum_{c=0..78}(79-c)

// ---- exact-order f32 IoU matching the JAX reference elementwise ops ----
__device__ __forceinline__ float iou_ref(float4 a, float4 b) {
  float areaA = __fmul_rn(__fsub_rn(a.z, a.x), __fsub_rn(a.w, a.y));
  float areaB = __fmul_rn(__fsub_rn(b.z, b.x), __fsub_rn(b.w, b.y));
  float iw = fmaxf(__fsub_rn(fminf(a.z, b.z), fmaxf(a.x, b.x)), 0.0f);
  float ih = fmaxf(__fsub_rn(fminf(a.w, b.w), fmaxf(a.y, b.y)), 0.0f);
  float inter = __fmul_rn(iw, ih);
  float denom = __fsub_rn(__fadd_rn(areaA, areaB), inter);
  return inter / denom;  // 0/0 -> NaN for zero-pad boxes; NaN>0.3f is false (safe)
}

// triangular row offset (in u64 words) of mask row i within one image
__device__ __forceinline__ int row_off_words(int i) {
  int ci = i >> 6;
  int r = i & 63;
  int base = ((ci * 79 - ((ci * (ci - 1)) >> 1)) << 6);
  return base + r * (79 - ci);
}

__device__ __forceinline__ u64 wave_or64(u64 x) {
  for (int d = 1; d < 64; d <<= 1) x |= __shfl_xor(x, d);
  return x;
}

__global__ void k_zero(float* out, u32* hist, u32* cnt) {
  int t = blockIdx.x * 256 + threadIdx.x;
  if (t < 30000) out[t] = 0.0f;
  if (t < 4096) hist[t] = 0u;
  if (t < 4) cnt[t] = 0u;
}

__global__ void k_decode(const float4* loc, const float* conf, const float4* prior,
                         float4* dec, u32* hist) {
  int p = blockIdx.x * 256 + threadIdx.x;
  int img = blockIdx.y;
  if (p >= NP) return;
  float4 L = loc[(size_t)img * NP + p];
  float4 Pr = prior[p];
  // xy = prior_xy + (loc_xy * 0.1) * prior_wh   (no FMA contraction: explicit _rn ops)
  float ex = __fmul_rn(__fmul_rn(L.x, 0.1f), Pr.z);
  float ey = __fmul_rn(__fmul_rn(L.y, 0.1f), Pr.w);
  float cx = __fadd_rn(Pr.x, ex);
  float cy = __fadd_rn(Pr.y, ey);
  // wh = prior_wh * exp(loc_wh * 0.2) ; exp via double = correctly-rounded f32 exp
  float ww = __fmul_rn(Pr.z, (float)exp((double)__fmul_rn(L.z, 0.2f)));
  float hh = __fmul_rn(Pr.w, (float)exp((double)__fmul_rn(L.w, 0.2f)));
  float x1 = __fsub_rn(cx, __fmul_rn(ww, 0.5f));
  float y1 = __fsub_rn(cy, __fmul_rn(hh, 0.5f));
  float x2 = __fadd_rn(x1, ww);
  float y2 = __fadd_rn(y1, hh);
  dec[(size_t)img * NP + p] = make_float4(x1, y1, x2, y2);
  float s = conf[((size_t)img * NP + p) * 2 + 1];
  if (s > 0.05f) {
    int bin = (int)(s * 1024.0f); if (bin > 1023) bin = 1023;
    atomicAdd(&hist[img * 1024 + bin], 1u);
  }
}

// one wave per image: find cutoff bin so that suffix-count >= NTOP
__global__ __launch_bounds__(64) void k_cutoff(const u32* hist, int* cut) {
  int img = blockIdx.x;
  int lane = threadIdx.x;
  const u32* h = hist + img * 1024;
  int start = 1023 - lane * 16;  // lane covers bins [start-15, start], descending order
  int local = 0;
  for (int q = 0; q < 16; ++q) local += (int)h[start - q];
  int incl = local;
  for (int d = 1; d < 64; d <<= 1) {
    int v = __shfl_up(incl, d);
    if (lane >= d) incl += v;
  }
  u64 hit = __ballot(incl >= NTOP);
  if (hit != 0ull) {
    int f = __builtin_ctzll(hit);
    if (lane == f) {
      int acc = incl - local;
      int cb = 0;
      for (int q = 0; q < 16; ++q) {
        acc += (int)h[start - q];
        if (acc >= NTOP) { cb = start - q; break; }
      }
      cut[img] = cb;
    }
  } else if (lane == 0) {
    cut[img] = 0;  // fewer than NTOP valid scores
  }
}

// per image: collect candidates, bitonic-sort 8192 u64 keys in dynamic LDS,
// emit sorted top-5000 (score, box) + validity bitmask
__global__ __launch_bounds__(1024) void k_select(const float* conf, const int* cut, u32* cnt,
                                                 const float4* dec, float* tscore,
                                                 float4* tbox, u64* vmask) {
  extern __shared__ u64 keys[];  // 8192 * 8B = 64KB
  int img = blockIdx.x;
  int tid = threadIdx.x;
  int lane = tid & 63;
  int cb = cut[img];
  for (int i = tid; i < SORTN; i += 1024) keys[i] = ~0ull;
  __syncthreads();
  // collect candidates (wave-aggregated global atomic for positions)
  for (int p = tid; p < NP; p += 1024) {
    float s = conf[((size_t)img * NP + p) * 2 + 1];
    bool take = false;
    if (s > 0.05f) {
      int bin = (int)(s * 1024.0f); if (bin > 1023) bin = 1023;
      take = (bin >= cb);
    }
    if (take) {
      u64 m = __ballot(1);
      int leader = __builtin_ctzll(m);
      int rank = __builtin_popcountll(m & ((1ull << lane) - 1ull));
      int base = 0;
      if (lane == leader) base = (int)atomicAdd(&cnt[img], (u32)__builtin_popcountll(m));
      base = __shfl(base, leader);
      int pos = base + rank;
      if (pos < SORTN)
        keys[pos] = (((u64)(~__float_as_uint(s))) << 32) | (u32)p;
    }
  }
  __syncthreads();
  // bitonic sort ascending: key = (~score_bits, idx) => score desc, idx asc (lax.top_k ties)
  for (int k = 2; k <= SORTN; k <<= 1) {
    for (int j = k >> 1; j > 0; j >>= 1) {
      for (int idx = tid; idx < SORTN; idx += 1024) {
        int ixj = idx ^ j;
        if (ixj > idx) {
          u64 a = keys[idx], b = keys[ixj];
          bool up = ((idx & k) == 0);
          if ((a > b) == up) { keys[idx] = b; keys[ixj] = a; }
        }
      }
      __syncthreads();
    }
  }
  // emit top-5000
  for (int i = tid; i < NTOP; i += 1024) {
    u64 key = keys[i];
    u32 sb = ~(u32)(key >> 32);
    float s = __uint_as_float(sb);
    u32 pidx = (u32)(key & 0xffffffffu);
    tscore[img * TPAD + i] = s;
    float4 bx;
    if (key != ~0ull) bx = dec[(size_t)img * NP + pidx];
    else bx = make_float4(0.f, 0.f, 0.f, 0.f);
    tbox[img * TPAD + i] = bx;
    bool valid = (key != ~0ull) && (s > 0.05f);
    u64 bal = __ballot(valid);
    if (lane == 0) vmask[img * 80 + (i >> 6)] = bal;  // wave == one 64-aligned word
  }
}

// parallel suppression-bitmask: 64x64 tiles, upper triangle, triangular storage
__global__ __launch_bounds__(64) void k_mask(const float4* tbox, u64* mask) {
  int ci = blockIdx.x, cj = blockIdx.y, img = blockIdx.z;
  if (cj < ci) return;
  int lane = threadIdx.x;
  __shared__ float4 jb[64];
  int j0 = cj * 64;
  int jj = j0 + lane;
  jb[lane] = (jj < NTOP) ? tbox[img * TPAD + jj] : make_float4(0.f, 0.f, 0.f, 0.f);
  __syncthreads();
  int i = ci * 64 + lane;
  if (i >= NTOP) return;
  float4 bi = tbox[img * TPAD + i];
  u64 word = 0;
  for (int q = 0; q < 64; ++q) {
    int j = j0 + q;
    if (j > i && j < NTOP) {
      if (iou_ref(bi, jb[q]) > 0.3f) word |= (1ull << q);
    }
  }
  u64* mrow = mask + (size_t)img * MWORDS + row_off_words(i);
  mrow[cj - ci] = word;
}

// greedy NMS, column-pull form: one wave per image.
// At word f, rem[f] is computed by gathering mask[i][f] for ALL kept boxes i
// so far (one word per kept box, all loads independent and in flight
// together), then one wave_or64. The intra-word greedy fixpoint runs on the
// diagonal tile in registers. Serial chain = ONE gather latency per
// 64-candidate word-block, not one per kept box.
__global__ __launch_bounds__(64) void k_nms(const float* tscore, const float4* tbox,
                                            const u64* vmask, const u64* mask, float* out) {
  int img = blockIdx.x;
  int lane = threadIdx.x;
  const u64* mimg = mask + (size_t)img * MWORDS;

  u64 vld_lo = (lane < NW) ? vmask[img * 80 + lane] : 0ull;
  u64 vld_hi = (lane + 64 < NW) ? vmask[img * 80 + lane + 64] : 0ull;

  __shared__ int list[TOPK];
  int nk = 0;

  // prefetch diagonal tile of word 0: lane k holds self-word of row k
  u64 mydiag = mimg[row_off_words(lane)];

  for (int f = 0; f < NW; ++f) {
    u64 vldf = (f < 64) ? __shfl(vld_lo, f) : __shfl(vld_hi, f - 64);
    u64 diag = mydiag;

    // prefetch next word's diagonal (overlaps with gather + resolve)
    if (f + 1 < NW) {
      int i1 = ((f + 1) << 6) + lane;
      mydiag = (i1 < NTOP) ? mimg[row_off_words(i1)] : 0ull;
    }

    // ---- column-pull gather: rem_f = OR over kept i of mask[i][f] ----
    // hand-unrolled x2 with clamped indices so loads stay in flight
    u64 acc0 = 0ull, acc1 = 0ull;
    int nkm1 = nk - 1;
    for (int r0 = 0; r0 < nk; r0 += 128) {
      int ra = r0 + lane;
      int rb = ra + 64;
      int ia = list[ra < nkm1 ? ra : nkm1];
      int ib = list[rb < nkm1 ? rb : nkm1];
      u64 va = mimg[row_off_words(ia) + (f - (ia >> 6))];
      u64 vb = mimg[row_off_words(ib) + (f - (ib >> 6))];
      if (ra <= nkm1) acc0 |= va;
      if (rb <= nkm1) acc1 |= vb;
    }
    u64 remf = wave_or64(acc0 | acc1);

    u64 live = vldf & ~remf;
    if (live == 0ull) continue;

    // intra-word greedy fixpoint (final kept mask in ascending bit order
    // == greedy keep order within the word)
    u64 kept = 0ull;
    while (live) {
      u64 contrib = ((live >> lane) & 1ull) ? diag : 0ull;
      u64 supany = wave_or64(contrib);
      u64 ready = live & ~supany;          // no live lower overlapper -> kept
      kept |= ready;
      u64 contrib2 = ((ready >> lane) & 1ull) ? diag : 0ull;
      u64 supready = wave_or64(contrib2);
      live &= ~(ready | supready);
    }

    // append kept (ascending index) to list, honoring the 750 cut
    int cap = TOPK - nk;
    int rank = __builtin_popcountll(kept & ((1ull << lane) - 1ull));
    if (((kept >> lane) & 1ull) && rank < cap) list[nk + rank] = (f << 6) + lane;
    int nkw = __builtin_popcountll(kept);
    nk += (nkw < cap) ? nkw : cap;
    if (nk >= TOPK) break;
  }

  __syncthreads();
  float* o = out + (size_t)(img * 2 + 1) * TOPK * 5;
  for (int r = lane; r < nk; r += 64) {
    int i = list[r];
    float s = tscore[img * TPAD + i];
    float4 b = tbox[img * TPAD + i];
    o[r * 5 + 0] = s;
    o[r * 5 + 1] = b.x;
    o[r * 5 + 2] = b.y;
    o[r * 5 + 3] = b.z;
    o[r * 5 + 4] = b.w;
  }
}

extern "C" void kernel_launch(void* const* d_in, const int* in_sizes, int n_in,
                              void* d_out, int out_size, void* d_ws, size_t ws_size,
                              hipStream_t stream) {
  const float4* loc   = (const float4*)d_in[0];
  const float*  conf  = (const float*)d_in[1];
  const float4* prior = (const float4*)d_in[2];
  float* out = (float*)d_out;
  char* ws = (char*)d_ws;

  // ws layout (256B-aligned offsets), total ~8.7MB
  float4* dec    = (float4*)(ws + 0);          // 4*34125*16 = 2,184,000
  u32*    hist   = (u32*)  (ws + 2184192);     // 4*1024*4   = 16,384
  u32*    cnt    = (u32*)  (ws + 2200576);     // 16
  int*    cut    = (int*)  (ws + 2200832);     // 16
  float*  tscore = (float*)(ws + 2201088);     // 4*5120*4   = 81,920
  float4* tbox   = (float4*)(ws + 2283008);    // 4*5120*16  = 327,680
  u64*    vmaskp = (u64*)  (ws + 2610688);     // 4*80*8     = 2,560
  u64*    maskp  = (u64*)  (ws + 2613504);     // 4*202240*8 = 6,471,680  -> end 9,085,184

  k_zero<<<dim3(118), 256, 0, stream>>>(out, hist, cnt);
  k_decode<<<dim3((NP + 255) / 256, NB), 256, 0, stream>>>(loc, conf, prior, dec, hist);
  k_cutoff<<<NB, 64, 0, stream>>>(hist, cut);
  k_select<<<NB, 1024, SORTN * sizeof(u64), stream>>>(conf, cut, cnt, dec, tscore, tbox, vmaskp);
  k_mask<<<dim3(NW, NW, NB), 64, 0, stream>>>(tbox, maskp);
  k_nms<<<NB, 64, 0, stream>>>(tscore, tbox, vmaskp, maskp, out);
}

// Round 4
// 390.672 us; speedup vs baseline: 1.4568x; 1.0604x over previous
//
#include <hip/hip_runtime.h>
#include <math.h>

typedef unsigned long long u64;
typedef unsigned int u32;

#define NP 34125
#define NB 4
#define NTOP 5000
#define TOPK 750
#define NW 79          // ceil(5000/64)
#define TPAD 5120      // padded top-K stride
#define SORTN 8192
#define MWORDS 202240  // triangular mask words per image: 64*sum_{c=0..78}(79-c)

// ---- exact-order f32 IoU matching the JAX reference elementwise ops ----
__device__ __forceinline__ float iou_ref(float4 a, float4 b) {
  float areaA = __fmul_rn(__fsub_rn(a.z, a.x), __fsub_rn(a.w, a.y));
  float areaB = __fmul_rn(__fsub_rn(b.z, b.x), __fsub_rn(b.w, b.y));
  float iw = fmaxf(__fsub_rn(fminf(a.z, b.z), fmaxf(a.x, b.x)), 0.0f);
  float ih = fmaxf(__fsub_rn(fminf(a.w, b.w), fmaxf(a.y, b.y)), 0.0f);
  float inter = __fmul_rn(iw, ih);
  float denom = __fsub_rn(__fadd_rn(areaA, areaB), inter);
  return inter / denom;  // 0/0 -> NaN for zero-pad boxes; NaN>0.3f is false (safe)
}

// triangular row offset (in u64 words) of mask row i within one image
__device__ __forceinline__ int row_off_words(int i) {
  int ci = i >> 6;
  int r = i & 63;
  int base = ((ci * 79 - ((ci * (ci - 1)) >> 1)) << 6);
  return base + r * (79 - ci);
}

__device__ __forceinline__ u64 wave_or64(u64 x) {
  for (int d = 1; d < 64; d <<= 1) x |= __shfl_xor(x, d);
  return x;
}

__global__ void k_zero(float* out, u32* hist, u32* cnt) {
  int t = blockIdx.x * 256 + threadIdx.x;
  if (t < 30000) out[t] = 0.0f;
  if (t < 4096) hist[t] = 0u;
  if (t < 4) cnt[t] = 0u;
}

__global__ void k_decode(const float4* loc, const float* conf, const float4* prior,
                         float4* dec, u32* hist) {
  int p = blockIdx.x * 256 + threadIdx.x;
  int img = blockIdx.y;
  if (p >= NP) return;
  float4 L = loc[(size_t)img * NP + p];
  float4 Pr = prior[p];
  // xy = prior_xy + (loc_xy * 0.1) * prior_wh   (no FMA contraction: explicit _rn ops)
  float ex = __fmul_rn(__fmul_rn(L.x, 0.1f), Pr.z);
  float ey = __fmul_rn(__fmul_rn(L.y, 0.1f), Pr.w);
  float cx = __fadd_rn(Pr.x, ex);
  float cy = __fadd_rn(Pr.y, ey);
  // wh = prior_wh * exp(loc_wh * 0.2) ; exp via double = correctly-rounded f32 exp
  float ww = __fmul_rn(Pr.z, (float)exp((double)__fmul_rn(L.z, 0.2f)));
  float hh = __fmul_rn(Pr.w, (float)exp((double)__fmul_rn(L.w, 0.2f)));
  float x1 = __fsub_rn(cx, __fmul_rn(ww, 0.5f));
  float y1 = __fsub_rn(cy, __fmul_rn(hh, 0.5f));
  float x2 = __fadd_rn(x1, ww);
  float y2 = __fadd_rn(y1, hh);
  dec[(size_t)img * NP + p] = make_float4(x1, y1, x2, y2);
  float s = conf[((size_t)img * NP + p) * 2 + 1];
  if (s > 0.05f) {
    int bin = (int)(s * 1024.0f); if (bin > 1023) bin = 1023;
    atomicAdd(&hist[img * 1024 + bin], 1u);
  }
}

// one wave per image: find cutoff bin so that suffix-count >= NTOP
__global__ __launch_bounds__(64) void k_cutoff(const u32* hist, int* cut) {
  int img = blockIdx.x;
  int lane = threadIdx.x;
  const u32* h = hist + img * 1024;
  int start = 1023 - lane * 16;  // lane covers bins [start-15, start], descending order
  int local = 0;
  for (int q = 0; q < 16; ++q) local += (int)h[start - q];
  int incl = local;
  for (int d = 1; d < 64; d <<= 1) {
    int v = __shfl_up(incl, d);
    if (lane >= d) incl += v;
  }
  u64 hit = __ballot(incl >= NTOP);
  if (hit != 0ull) {
    int f = __builtin_ctzll(hit);
    if (lane == f) {
      int acc = incl - local;
      int cb = 0;
      for (int q = 0; q < 16; ++q) {
        acc += (int)h[start - q];
        if (acc >= NTOP) { cb = start - q; break; }
      }
      cut[img] = cb;
    }
  } else if (lane == 0) {
    cut[img] = 0;  // fewer than NTOP valid scores
  }
}

// per image: collect candidates, bitonic-sort 8192 u64 keys in dynamic LDS,
// emit sorted top-5000 (score, box) + validity bitmask
__global__ __launch_bounds__(1024) void k_select(const float* conf, const int* cut, u32* cnt,
                                                 const float4* dec, float* tscore,
                                                 float4* tbox, u64* vmask) {
  extern __shared__ u64 keys[];  // 8192 * 8B = 64KB
  int img = blockIdx.x;
  int tid = threadIdx.x;
  int lane = tid & 63;
  int cb = cut[img];
  for (int i = tid; i < SORTN; i += 1024) keys[i] = ~0ull;
  __syncthreads();
  // collect candidates (wave-aggregated global atomic for positions)
  for (int p = tid; p < NP; p += 1024) {
    float s = conf[((size_t)img * NP + p) * 2 + 1];
    bool take = false;
    if (s > 0.05f) {
      int bin = (int)(s * 1024.0f); if (bin > 1023) bin = 1023;
      take = (bin >= cb);
    }
    if (take) {
      u64 m = __ballot(1);
      int leader = __builtin_ctzll(m);
      int rank = __builtin_popcountll(m & ((1ull << lane) - 1ull));
      int base = 0;
      if (lane == leader) base = (int)atomicAdd(&cnt[img], (u32)__builtin_popcountll(m));
      base = __shfl(base, leader);
      int pos = base + rank;
      if (pos < SORTN)
        keys[pos] = (((u64)(~__float_as_uint(s))) << 32) | (u32)p;
    }
  }
  __syncthreads();
  // bitonic sort ascending: key = (~score_bits, idx) => score desc, idx asc (lax.top_k ties)
  for (int k = 2; k <= SORTN; k <<= 1) {
    for (int j = k >> 1; j > 0; j >>= 1) {
      for (int idx = tid; idx < SORTN; idx += 1024) {
        int ixj = idx ^ j;
        if (ixj > idx) {
          u64 a = keys[idx], b = keys[ixj];
          bool up = ((idx & k) == 0);
          if ((a > b) == up) { keys[idx] = b; keys[ixj] = a; }
        }
      }
      __syncthreads();
    }
  }
  // emit top-5000
  for (int i = tid; i < NTOP; i += 1024) {
    u64 key = keys[i];
    u32 sb = ~(u32)(key >> 32);
    float s = __uint_as_float(sb);
    u32 pidx = (u32)(key & 0xffffffffu);
    tscore[img * TPAD + i] = s;
    float4 bx;
    if (key != ~0ull) bx = dec[(size_t)img * NP + pidx];
    else bx = make_float4(0.f, 0.f, 0.f, 0.f);
    tbox[img * TPAD + i] = bx;
    bool valid = (key != ~0ull) && (s > 0.05f);
    u64 bal = __ballot(valid);
    if (lane == 0) vmask[img * 80 + (i >> 6)] = bal;  // wave == one 64-aligned word
  }
}

// parallel suppression-bitmask: 64x64 tiles, upper triangle, triangular storage.
// Diagonal blocks additionally emit the TRANSPOSED tile (lane l holds column l:
// bit k = "k suppresses l"), built with 64 ballots.
__global__ __launch_bounds__(64) void k_mask(const float4* tbox, u64* mask, u64* diagT) {
  int ci = blockIdx.x, cj = blockIdx.y, img = blockIdx.z;
  if (cj < ci) return;
  int lane = threadIdx.x;
  __shared__ float4 jb[64];
  int j0 = cj * 64;
  int jj = j0 + lane;
  jb[lane] = (jj < NTOP) ? tbox[img * TPAD + jj] : make_float4(0.f, 0.f, 0.f, 0.f);
  __syncthreads();
  int i = ci * 64 + lane;
  if (i >= NTOP) return;
  float4 bi = tbox[img * TPAD + i];
  u64 word = 0;
  for (int q = 0; q < 64; ++q) {
    int j = j0 + q;
    if (j > i && j < NTOP) {
      if (iou_ref(bi, jb[q]) > 0.3f) word |= (1ull << q);
    }
  }
  u64* mrow = mask + (size_t)img * MWORDS + row_off_words(i);
  mrow[cj - ci] = word;
  if (ci == cj) {
    u64 colw = 0ull;
    for (int t = 0; t < 64; ++t) {
      u64 b = __ballot((word >> t) & 1ull);  // bit l of b = row l's bit t => column t
      if (lane == t) colw = b;
    }
    diagT[((size_t)img * 80 + ci) * 64 + lane] = colw;
  }
}

// greedy NMS, column-pull + transposed-diag form: one wave per image.
// Per word f: (1) pull-gather rem[f] = OR of mask[i][f] over ALL kept i with a
// fixed-unroll tiered load (1/4/12 x 64, clamped) so every load is in flight
// before ONE wait -> one memory latency per word. (2) serial greedy over kept
// bits using ballots on the transposed diagonal tile: per kept box ~25cy, no
// shuffles, iteration count = keeps-in-word.
__global__ __launch_bounds__(64) void k_nms(const float* tscore, const float4* tbox,
                                            const u64* vmask, const u64* mask,
                                            const u64* diagT, float* out) {
  int img = blockIdx.x;
  int lane = threadIdx.x;
  const u64* mimg = mask + (size_t)img * MWORDS;
  const u64* dT = diagT + (size_t)img * 80 * 64;

  u64 vld_lo = (lane < NW) ? vmask[img * 80 + lane] : 0ull;
  u64 vld_hi = (lane + 64 < NW) ? vmask[img * 80 + lane + 64] : 0ull;

  __shared__ int list[TOPK];
  int nk = 0;

  u64 mycol = dT[lane];  // transposed diag of word 0, column `lane`

  for (int f = 0; f < NW; ++f) {
    u64 vldf = (f < 64) ? __shfl(vld_lo, f) : __shfl(vld_hi, f - 64);
    u64 colT = mycol;
    // prefetch next word's transposed diag (overlaps gather + greedy)
    if (f + 1 < NW) mycol = dT[(f + 1) * 64 + lane];

    // ---- pull-gather: rem_f = OR over kept i of mask[i][f] ----
    u64 remf = 0ull;
    if (nk > 0) {
      int nkm1 = nk - 1;
      u64 acc = 0ull;
      if (nk <= 64) {
        int r = lane < nkm1 ? lane : nkm1;
        int i = list[r];
        u64 g0 = mimg[row_off_words(i) + (f - (i >> 6))];
        if (lane <= nkm1) acc = g0;
      } else if (nk <= 256) {
        u64 g[4];
#pragma unroll
        for (int u = 0; u < 4; ++u) {
          int r = u * 64 + lane; r = r < nkm1 ? r : nkm1;
          int i = list[r];
          g[u] = mimg[row_off_words(i) + (f - (i >> 6))];
        }
#pragma unroll
        for (int u = 0; u < 4; ++u) if (u * 64 + lane <= nkm1) acc |= g[u];
      } else {
        u64 g[12];
#pragma unroll
        for (int u = 0; u < 12; ++u) {
          int r = u * 64 + lane; r = r < nkm1 ? r : nkm1;
          int i = list[r];
          g[u] = mimg[row_off_words(i) + (f - (i >> 6))];
        }
#pragma unroll
        for (int u = 0; u < 12; ++u) if (u * 64 + lane <= nkm1) acc |= g[u];
      }
      remf = wave_or64(acc);
    }

    u64 live = vldf & ~remf;
    if (live == 0ull) continue;

    // ---- serial greedy, ballot-based suppression ----
    u64 kept = 0ull;
    while (live) {
      int k = __builtin_ctzll(live);
      kept |= (1ull << k);
      u64 sup = __ballot((colT >> k) & 1ull);  // bit l = "k suppresses l" (l>k only)
      live &= ~((1ull << k) | sup);
    }

    // append kept (ascending index) to list, honoring the 750 cut
    int cap = TOPK - nk;
    int rank = __builtin_popcountll(kept & ((1ull << lane) - 1ull));
    if (((kept >> lane) & 1ull) && rank < cap) list[nk + rank] = (f << 6) + lane;
    int nkw = __builtin_popcountll(kept);
    nk += (nkw < cap) ? nkw : cap;
    if (nk >= TOPK) break;
  }

  __syncthreads();
  float* o = out + (size_t)(img * 2 + 1) * TOPK * 5;
  for (int r = lane; r < nk; r += 64) {
    int i = list[r];
    float s = tscore[img * TPAD + i];
    float4 b = tbox[img * TPAD + i];
    o[r * 5 + 0] = s;
    o[r * 5 + 1] = b.x;
    o[r * 5 + 2] = b.y;
    o[r * 5 + 3] = b.z;
    o[r * 5 + 4] = b.w;
  }
}

extern "C" void kernel_launch(void* const* d_in, const int* in_sizes, int n_in,
                              void* d_out, int out_size, void* d_ws, size_t ws_size,
                              hipStream_t stream) {
  const float4* loc   = (const float4*)d_in[0];
  const float*  conf  = (const float*)d_in[1];
  const float4* prior = (const float4*)d_in[2];
  float* out = (float*)d_out;
  char* ws = (char*)d_ws;

  // ws layout (256B-aligned offsets), total ~9.25MB
  float4* dec    = (float4*)(ws + 0);          // 4*34125*16 = 2,184,000
  u32*    hist   = (u32*)  (ws + 2184192);     // 4*1024*4   = 16,384
  u32*    cnt    = (u32*)  (ws + 2200576);     // 16
  int*    cut    = (int*)  (ws + 2200832);     // 16
  float*  tscore = (float*)(ws + 2201088);     // 4*5120*4   = 81,920
  float4* tbox   = (float4*)(ws + 2283008);    // 4*5120*16  = 327,680
  u64*    vmaskp = (u64*)  (ws + 2610688);     // 4*80*8     = 2,560
  u64*    maskp  = (u64*)  (ws + 2613504);     // 4*202240*8 = 6,471,680  -> 9,085,184
  u64*    diagTp = (u64*)  (ws + 9085184);     // 4*80*64*8  = 163,840    -> 9,249,024

  k_zero<<<dim3(118), 256, 0, stream>>>(out, hist, cnt);
  k_decode<<<dim3((NP + 255) / 256, NB), 256, 0, stream>>>(loc, conf, prior, dec, hist);
  k_cutoff<<<NB, 64, 0, stream>>>(hist, cut);
  k_select<<<NB, 1024, SORTN * sizeof(u64), stream>>>(conf, cut, cnt, dec, tscore, tbox, vmaskp);
  k_mask<<<dim3(NW, NW, NB), 64, 0, stream>>>(tbox, maskp, diagTp);
  k_nms<<<NB, 64, 0, stream>>>(tscore, tbox, vmaskp, maskp, diagTp, out);
}

// Round 5
// 274.755 us; speedup vs baseline: 2.0715x; 1.4219x over previous
//
#include <hip/hip_runtime.h>
#include <math.h>

typedef unsigned long long u64;
typedef unsigned int u32;

#define NP 34125
#define NB 4
#define NTOP 5000
#define TOPK 750
#define NW 79          // ceil(5000/64)
#define TPAD 5120      // padded top-K stride
#define CAP 8192       // slot capacity per image for counting-sort scatter
#define MWORDS 202240  // triangular mask words per image: 64*sum_{c=0..78}(79-c)

// ---- exact-order f32 IoU matching the JAX reference elementwise ops ----
__device__ __forceinline__ float iou_ref(float4 a, float4 b) {
  float areaA = __fmul_rn(__fsub_rn(a.z, a.x), __fsub_rn(a.w, a.y));
  float areaB = __fmul_rn(__fsub_rn(b.z, b.x), __fsub_rn(b.w, b.y));
  float iw = fmaxf(__fsub_rn(fminf(a.z, b.z), fmaxf(a.x, b.x)), 0.0f);
  float ih = fmaxf(__fsub_rn(fminf(a.w, b.w), fmaxf(a.y, b.y)), 0.0f);
  float inter = __fmul_rn(iw, ih);
  float denom = __fsub_rn(__fadd_rn(areaA, areaB), inter);
  return inter / denom;  // 0/0 -> NaN for zero-pad boxes; NaN>0.3f is false (safe)
}

// triangular row offset (in u64 words) of mask row i within one image
__device__ __forceinline__ int row_off_words(int i) {
  int ci = i >> 6;
  int r = i & 63;
  int base = ((ci * 79 - ((ci * (ci - 1)) >> 1)) << 6);
  return base + r * (79 - ci);
}

__global__ void k_zero(float* out, u32* hist, u32* bcnt, int* cut, u64* keys) {
  int t = blockIdx.x * 256 + threadIdx.x;
  if (t < 30000) out[t] = 0.0f;
  if (t < 4096) { hist[t] = 0u; bcnt[t] = 0u; }
  if (t < 4) cut[t] = 0;
  if (t < NB * CAP) keys[t] = ~0ull;
}

__global__ void k_decode(const float4* loc, const float* conf, const float4* prior,
                         float4* dec, u32* hist) {
  int p = blockIdx.x * 256 + threadIdx.x;
  int img = blockIdx.y;
  if (p >= NP) return;
  float4 L = loc[(size_t)img * NP + p];
  float4 Pr = prior[p];
  // xy = prior_xy + (loc_xy * 0.1) * prior_wh   (no FMA contraction: explicit _rn ops)
  float ex = __fmul_rn(__fmul_rn(L.x, 0.1f), Pr.z);
  float ey = __fmul_rn(__fmul_rn(L.y, 0.1f), Pr.w);
  float cx = __fadd_rn(Pr.x, ex);
  float cy = __fadd_rn(Pr.y, ey);
  // wh = prior_wh * exp(loc_wh * 0.2) ; exp via double = correctly-rounded f32 exp
  float ww = __fmul_rn(Pr.z, (float)exp((double)__fmul_rn(L.z, 0.2f)));
  float hh = __fmul_rn(Pr.w, (float)exp((double)__fmul_rn(L.w, 0.2f)));
  float x1 = __fsub_rn(cx, __fmul_rn(ww, 0.5f));
  float y1 = __fsub_rn(cy, __fmul_rn(hh, 0.5f));
  float x2 = __fadd_rn(x1, ww);
  float y2 = __fadd_rn(y1, hh);
  dec[(size_t)img * NP + p] = make_float4(x1, y1, x2, y2);
  float s = conf[((size_t)img * NP + p) * 2 + 1];
  if (s > 0.05f) {
    int bin = (int)(s * 1024.0f); if (bin > 1023) bin = 1023;
    atomicAdd(&hist[img * 1024 + bin], 1u);
  }
}

// per image: suffix-scan the 1024-bin histogram -> descending-order base
// position per bin, plus the cutoff bin (suffix count crosses NTOP)
__global__ __launch_bounds__(1024) void k_prefix(const u32* hist, u32* sbase, int* cut) {
  __shared__ u32 buf[1024];
  int img = blockIdx.x, tid = threadIdx.x;
  int b = 1023 - tid;
  u32 c = hist[img * 1024 + b];
  buf[tid] = c;
  __syncthreads();
  for (int off = 1; off < 1024; off <<= 1) {
    u32 v = (tid >= off) ? buf[tid - off] : 0u;
    __syncthreads();
    buf[tid] += v;
    __syncthreads();
  }
  u32 S = buf[tid];                 // inclusive suffix count for bin b
  sbase[img * 1024 + b] = S - c;    // # elements in strictly-higher bins
  if (S >= NTOP && (S - c) < NTOP) cut[img] = b;  // unique crossing thread
}

// scatter each above-cutoff candidate to its exact descending position
// (bin base + arrival rank); within-bin order fixed later by k_binsort
__global__ void k_scatter(const float* conf, const u32* sbase, const int* cut,
                          u32* bcnt, u64* keys) {
  int p = blockIdx.x * 256 + threadIdx.x;
  int img = blockIdx.y;
  if (p >= NP) return;
  float s = conf[((size_t)img * NP + p) * 2 + 1];
  if (!(s > 0.05f)) return;
  int bin = (int)(s * 1024.0f); if (bin > 1023) bin = 1023;
  if (bin < cut[img]) return;
  u32 r = atomicAdd(&bcnt[img * 1024 + bin], 1u);
  u32 slot = sbase[img * 1024 + bin] + r;
  if (slot < CAP)
    keys[(size_t)img * CAP + slot] = (((u64)(~__float_as_uint(s))) << 32) | (u32)p;
}

// full ascending sort of 64 u64 keys across one wave (21 shfl_xor steps)
__device__ __forceinline__ u64 sort64(u64 x, int lane) {
  for (int k = 2; k <= 64; k <<= 1) {
    for (int j = k >> 1; j > 0; j >>= 1) {
      u64 v = __shfl_xor(x, j);
      bool keepMin = (((lane & j) == 0) == ((lane & k) == 0));
      u64 mn = x < v ? x : v;
      u64 mx = x < v ? v : x;
      x = keepMin ? mn : mx;
    }
  }
  return x;
}

// one wave per bin: sort that bin's slot range in place
// key = (~score_bits, idx) ascending  => score desc, idx asc (lax.top_k ties)
__global__ __launch_bounds__(64) void k_binsort(const u32* sbase, const u32* bcnt,
                                                const int* cut, u64* keys) {
  int b = blockIdx.x, img = blockIdx.y;
  if (b < cut[img]) return;
  u32 n = bcnt[img * 1024 + b];
  if (n == 0) return;
  u32 base = sbase[img * 1024 + b];
  if (base >= CAP) return;
  if (n > CAP - base) n = CAP - base;
  u64* seg = keys + (size_t)img * CAP + base;
  int lane = threadIdx.x;
  if (n <= 64) {
    u64 key = (lane < (int)n) ? seg[lane] : ~0ull;
    key = sort64(key, lane);
    if (lane < (int)n) seg[lane] = key;
  } else {
    // rare fallback: in-LDS bitonic, single wave, up to 1024 elements
    __shared__ u64 sbuf[1024];
    if (n > 1024) n = 1024;
    int npow2 = 128;
    while (npow2 < (int)n) npow2 <<= 1;
    for (int t = lane; t < npow2; t += 64) sbuf[t] = (t < (int)n) ? seg[t] : ~0ull;
    __syncthreads();
    for (int k = 2; k <= npow2; k <<= 1) {
      for (int j = k >> 1; j > 0; j >>= 1) {
        for (int t = lane; t < npow2; t += 64) {
          int ixj = t ^ j;
          if (ixj > t) {
            u64 a = sbuf[t], bb = sbuf[ixj];
            bool up = ((t & k) == 0);
            if ((a > bb) == up) { sbuf[t] = bb; sbuf[ixj] = a; }
          }
        }
        __syncthreads();
      }
    }
    for (int t = lane; t < (int)n; t += 64) seg[t] = sbuf[t];
  }
}

// emit sorted top-5000: scores, gathered boxes, validity bitmask
__global__ __launch_bounds__(1024) void k_emit(const u64* keys, const float4* dec,
                                               float* tscore, float4* tbox, u64* vmask) {
  int img = blockIdx.x;
  int tid = threadIdx.x;
  int lane = tid & 63;
  const u64* kimg = keys + (size_t)img * CAP;
  for (int i = tid; i < NTOP; i += 1024) {
    u64 key = kimg[i];
    u32 sb = ~(u32)(key >> 32);
    float s = __uint_as_float(sb);
    u32 pidx = (u32)(key & 0xffffffffu);
    tscore[img * TPAD + i] = s;
    float4 bx;
    if (key != ~0ull) bx = dec[(size_t)img * NP + pidx];
    else bx = make_float4(0.f, 0.f, 0.f, 0.f);
    tbox[img * TPAD + i] = bx;
    bool valid = (key != ~0ull) && (s > 0.05f);
    u64 bal = __ballot(valid);
    if (lane == 0) vmask[img * 80 + (i >> 6)] = bal;
  }
}

// parallel suppression-bitmask: 64x64 tiles, upper triangle, triangular storage.
// Diagonal blocks additionally emit the TRANSPOSED tile (lane l holds column l:
// bit k = "k suppresses l"), built with 64 ballots.
__global__ __launch_bounds__(64) void k_mask(const float4* tbox, u64* mask, u64* diagT) {
  int ci = blockIdx.x, cj = blockIdx.y, img = blockIdx.z;
  if (cj < ci) return;
  int lane = threadIdx.x;
  __shared__ float4 jb[64];
  int j0 = cj * 64;
  int jj = j0 + lane;
  jb[lane] = (jj < NTOP) ? tbox[img * TPAD + jj] : make_float4(0.f, 0.f, 0.f, 0.f);
  __syncthreads();
  int i = ci * 64 + lane;
  if (i >= NTOP) return;
  float4 bi = tbox[img * TPAD + i];
  u64 word = 0;
  for (int q = 0; q < 64; ++q) {
    int j = j0 + q;
    if (j > i && j < NTOP) {
      if (iou_ref(bi, jb[q]) > 0.3f) word |= (1ull << q);
    }
  }
  u64* mrow = mask + (size_t)img * MWORDS + row_off_words(i);
  mrow[cj - ci] = word;
  if (ci == cj) {
    u64 colw = 0ull;
    for (int t = 0; t < 64; ++t) {
      u64 b = __ballot((word >> t) & 1ull);  // bit l of b = row l's bit t => column t
      if (lane == t) colw = b;
    }
    diagT[((size_t)img * 80 + ci) * 64 + lane] = colw;
  }
}

// greedy NMS: distributed-register rem (lane owns words lane, lane+64),
// transposed-diag ballot greedy (~20cy per kept box), and BATCHED row pushes:
// all kept rows' future words issued as coalesced loads (8 rows/batch) before
// one wait -> one L2 latency per 64-candidate word, 750 coalesced rows total.
__global__ __launch_bounds__(64) void k_nms(const float* tscore, const float4* tbox,
                                            const u64* vmask, const u64* mask,
                                            const u64* diagT, float* out) {
  int img = blockIdx.x;
  int lane = threadIdx.x;
  const u64* mimg = mask + (size_t)img * MWORDS;
  const u64* dT = diagT + (size_t)img * 80 * 64;

  u64 vld_lo = (lane < NW) ? vmask[img * 80 + lane] : 0ull;
  u64 vld_hi = (lane + 64 < NW) ? vmask[img * 80 + lane + 64] : 0ull;
  u64 rem_lo = 0ull, rem_hi = 0ull;

  __shared__ int list[TOPK];
  int nk = 0;

  u64 mycol = dT[lane];  // transposed diag of word 0, column `lane`

  for (int f = 0; f < NW; ++f) {
    u64 remf = (f < 64) ? __shfl(rem_lo, f) : __shfl(rem_hi, f - 64);
    u64 vldf = (f < 64) ? __shfl(vld_lo, f) : __shfl(vld_hi, f - 64);
    u64 colT = mycol;
    // prefetch next word's transposed diag (overlaps greedy + push)
    if (f + 1 < NW) mycol = dT[(f + 1) * 64 + lane];

    u64 live = vldf & ~remf;
    if (live == 0ull) continue;

    // ---- serial greedy, ballot-based suppression ----
    u64 kept = 0ull;
    while (live) {
      int k = __builtin_ctzll(live);
      kept |= (1ull << k);
      u64 sup = __ballot((colT >> k) & 1ull);  // bit l = "k suppresses l" (l>k only)
      live &= ~((1ull << k) | sup);
    }

    // append kept (ascending index) to list, honoring the 750 cut
    int cap = TOPK - nk;
    int rank = __builtin_popcountll(kept & ((1ull << lane) - 1ull));
    if (((kept >> lane) & 1ull) && rank < cap) list[nk + rank] = (f << 6) + lane;
    int nkw = __builtin_popcountll(kept);
    nk += (nkw < cap) ? nkw : cap;
    if (nk >= TOPK) break;

    // ---- batched push: OR all kept rows' future words into distributed rem ----
    int lw = lane - f;             // row[0] = word f; word `lane` at offset lane-f
    int hw = lane + 64 - f;
    bool lok = (lane > f);
    bool hok = (lane + 64 < NW);   // lane+64 > f always (f < 79 <= lane+64+...)
    u64 kk = kept;
    while (kk) {
      int last = (f << 6) + __builtin_ctzll(kk);
      u64 alo = 0ull, ahi = 0ull;
#pragma unroll
      for (int u = 0; u < 8; ++u) {
        int cur;
        if (kk) { cur = (f << 6) + __builtin_ctzll(kk); kk &= kk - 1ull; }
        else cur = last;           // duplicate last row; OR is idempotent
        last = cur;
        const u64* row = mimg + row_off_words(cur);
        u64 vlo = lok ? row[lw] : 0ull;
        u64 vhi = hok ? row[hw] : 0ull;
        alo |= vlo;
        ahi |= vhi;
      }
      rem_lo |= alo;
      rem_hi |= ahi;
    }
  }

  __syncthreads();
  float* o = out + (size_t)(img * 2 + 1) * TOPK * 5;
  for (int r = lane; r < nk; r += 64) {
    int i = list[r];
    float s = tscore[img * TPAD + i];
    float4 b = tbox[img * TPAD + i];
    o[r * 5 + 0] = s;
    o[r * 5 + 1] = b.x;
    o[r * 5 + 2] = b.y;
    o[r * 5 + 3] = b.z;
    o[r * 5 + 4] = b.w;
  }
}

extern "C" void kernel_launch(void* const* d_in, const int* in_sizes, int n_in,
                              void* d_out, int out_size, void* d_ws, size_t ws_size,
                              hipStream_t stream) {
  const float4* loc   = (const float4*)d_in[0];
  const float*  conf  = (const float*)d_in[1];
  const float4* prior = (const float4*)d_in[2];
  float* out = (float*)d_out;
  char* ws = (char*)d_ws;

  // ws layout (256B-aligned offsets), total ~9.55MB
  float4* dec    = (float4*)(ws + 0);          // 4*34125*16 = 2,184,000
  u32*    hist   = (u32*)  (ws + 2184192);     // 4*1024*4   = 16,384
  u32*    bcnt   = (u32*)  (ws + 2200576);     // 4*1024*4   = 16,384
  u32*    sbase  = (u32*)  (ws + 2216960);     // 4*1024*4   = 16,384
  int*    cut    = (int*)  (ws + 2233344);     // 16 (pad to 256)
  u64*    keys   = (u64*)  (ws + 2233600);     // 4*8192*8   = 262,144
  float*  tscore = (float*)(ws + 2495744);     // 4*5120*4   = 81,920
  float4* tbox   = (float4*)(ws + 2577664);    // 4*5120*16  = 327,680
  u64*    vmaskp = (u64*)  (ws + 2905344);     // 4*80*8     = 2,560 (pad to 2,908,160)
  u64*    maskp  = (u64*)  (ws + 2908160);     // 4*202240*8 = 6,471,680 -> 9,379,840
  u64*    diagTp = (u64*)  (ws + 9379840);     // 4*80*64*8  = 163,840   -> 9,543,680

  k_zero<<<dim3(128), 256, 0, stream>>>(out, hist, bcnt, cut, keys);
  k_decode<<<dim3((NP + 255) / 256, NB), 256, 0, stream>>>(loc, conf, prior, dec, hist);
  k_prefix<<<NB, 1024, 0, stream>>>(hist, sbase, cut);
  k_scatter<<<dim3((NP + 255) / 256, NB), 256, 0, stream>>>(conf, sbase, cut, bcnt, keys);
  k_binsort<<<dim3(1024, NB), 64, 0, stream>>>(sbase, bcnt, cut, keys);
  k_emit<<<NB, 1024, 0, stream>>>(keys, dec, tscore, tbox, vmaskp);
  k_mask<<<dim3(NW, NW, NB), 64, 0, stream>>>(tbox, maskp, diagTp);
  k_nms<<<NB, 64, 0, stream>>>(tscore, tbox, vmaskp, maskp, diagTp, out);
}